// Round 6
// baseline (65.517 us; speedup 1.0000x reference)
//
#include <hip/hip_runtime.h>

constexpr int TPB = 256;
constexpr int PAIRS_PER_BLOCK = 32;   // 8 lanes per pair, 256 threads

__device__ __forceinline__ float fast_tanh(float v) {
    // tanh(x) = 1 - 2/(exp(2x)+1); exact at +/-inf, ~ulp-level error
    float ex = __expf(2.0f * v);
    return 1.0f - 2.0f * __builtin_amdgcn_rcpf(ex + 1.0f);
}

template <int CTRL>
__device__ __forceinline__ float dppadd(float x) {
    return x + __int_as_float(__builtin_amdgcn_update_dpp(
        0, __float_as_int(x), CTRL, 0xf, 0xf, true));
}

// All-reduce over this pair's 8 lanes. Pair lanes are {quad q, quad q+2} of a
// 16-lane DPP row (i.e. lanes l and l+8 are the same pair), so:
//   row_ror:8 merges the pair's two quads (never touches the other pair),
//   then two quad_perm rotations finish the 4-lane all-reduce per quad.
__device__ __forceinline__ float sum8(float x) {
    x = dppadd<0x128>(x);  // row_ror:8
    x = dppadd<0x39>(x);   // quad_perm [1,2,3,0]
    x = dppadd<0x4E>(x);   // quad_perm [2,3,0,1]
    return x;
}

// Per undirected pair p (edges e1=p=(s->t), e2=opp_idx[p]):
//   Z = M1*Xs - M2*Xt  (4x32);  sims1 = 2*Z*Xs^T;  sims2 = -2*Z*Xt^T
//   out[e] = tanh(W1 @ vec(sims_e) + b1)
// 8 lanes per pair; lane slot owns h-columns [4*slot, 4*slot+4).
__global__ __launch_bounds__(TPB) void sheaf_p8_kernel(
    const float* __restrict__ x,          // (N, 4, 32)
    const float* __restrict__ Maps,       // (E, 4, 4)
    const float* __restrict__ W1,         // (16, 16)
    const float* __restrict__ b1,         // (16,)
    const int*   __restrict__ edge_index, // (2, E)
    const int*   __restrict__ opp_idx,    // (E,)
    float*       __restrict__ out,        // (E, 4, 4)
    int E, int EHALF)
{
    const int tid    = threadIdx.x;
    const int lane16 = tid & 15;
    const int row16  = tid >> 4;
    const int pinr   = (lane16 >> 2) & 1;                      // which pair in this row
    const int slot   = (lane16 & 3) | (((lane16 >> 3) & 1) << 2); // 0..7: h-chunk owner
    const int pair   = blockIdx.x * PAIRS_PER_BLOCK + row16 * 2 + pinr;
    if (pair >= EHALF) return;   // uniform across the pair's 8 lanes

    const int s  = edge_index[pair];
    const int t  = edge_index[E + pair];
    const int e2 = opp_idx[pair];

    // lane's 4 h-columns of Xs, Xt (16B per lane; 8 lanes cover each 128B row)
    const float* xu = x + (size_t)s * 128 + slot * 4;
    const float* xv = x + (size_t)t * 128 + slot * 4;
    float4 u[4], v[4];
    #pragma unroll
    for (int d = 0; d < 4; ++d) {
        u[d] = *(const float4*)(xu + d * 32);
        v[d] = *(const float4*)(xv + d * 32);
    }

    // lane's two W1 rows (outputs 2*slot, 2*slot+1) + biases
    const int p0 = 2 * slot;
    float wA[16], wB[16];
    {
        const float4* WpA = (const float4*)(W1 + p0 * 16);
        const float4* WpB = (const float4*)(W1 + (p0 + 1) * 16);
        #pragma unroll
        for (int q4 = 0; q4 < 4; ++q4) {
            float4 a = WpA[q4], b = WpB[q4];
            wA[q4*4+0] = a.x; wA[q4*4+1] = a.y; wA[q4*4+2] = a.z; wA[q4*4+3] = a.w;
            wB[q4*4+0] = b.x; wB[q4*4+1] = b.y; wB[q4*4+2] = b.z; wB[q4*4+3] = b.w;
        }
    }
    const float2 bb = *(const float2*)(b1 + p0);

    const float4* M1p = (const float4*)(Maps + (size_t)pair * 16);
    const float4* M2p = (const float4*)(Maps + (size_t)e2   * 16);

    // fused: as each r_q is reduced, accumulate straight into the 4 outputs
    float d1a = 0.f, d1b = 0.f, d2a = 0.f, d2b = 0.f;
    #pragma unroll
    for (int i = 0; i < 4; ++i) {
        const float4 m1 = M1p[i];
        const float4 m2 = M2p[i];
        // Z row i over lane's 4 h-cols
        float4 zi;
        zi.x = m1.x * u[0].x;            zi.y = m1.x * u[0].y;
        zi.z = m1.x * u[0].z;            zi.w = m1.x * u[0].w;
        zi.x = fmaf(m1.y, u[1].x, zi.x); zi.y = fmaf(m1.y, u[1].y, zi.y);
        zi.z = fmaf(m1.y, u[1].z, zi.z); zi.w = fmaf(m1.y, u[1].w, zi.w);
        zi.x = fmaf(m1.z, u[2].x, zi.x); zi.y = fmaf(m1.z, u[2].y, zi.y);
        zi.z = fmaf(m1.z, u[2].z, zi.z); zi.w = fmaf(m1.z, u[2].w, zi.w);
        zi.x = fmaf(m1.w, u[3].x, zi.x); zi.y = fmaf(m1.w, u[3].y, zi.y);
        zi.z = fmaf(m1.w, u[3].z, zi.z); zi.w = fmaf(m1.w, u[3].w, zi.w);
        zi.x = fmaf(-m2.x, v[0].x, zi.x); zi.y = fmaf(-m2.x, v[0].y, zi.y);
        zi.z = fmaf(-m2.x, v[0].z, zi.z); zi.w = fmaf(-m2.x, v[0].w, zi.w);
        zi.x = fmaf(-m2.y, v[1].x, zi.x); zi.y = fmaf(-m2.y, v[1].y, zi.y);
        zi.z = fmaf(-m2.y, v[1].z, zi.z); zi.w = fmaf(-m2.y, v[1].w, zi.w);
        zi.x = fmaf(-m2.z, v[2].x, zi.x); zi.y = fmaf(-m2.z, v[2].y, zi.y);
        zi.z = fmaf(-m2.z, v[2].z, zi.z); zi.w = fmaf(-m2.z, v[2].w, zi.w);
        zi.x = fmaf(-m2.w, v[3].x, zi.x); zi.y = fmaf(-m2.w, v[3].y, zi.y);
        zi.z = fmaf(-m2.w, v[3].z, zi.z); zi.w = fmaf(-m2.w, v[3].w, zi.w);

        #pragma unroll
        for (int k = 0; k < 4; ++k) {
            float pa = zi.x * u[k].x;
            pa = fmaf(zi.y, u[k].y, pa);
            pa = fmaf(zi.z, u[k].z, pa);
            pa = fmaf(zi.w, u[k].w, pa);
            float pb = zi.x * v[k].x;
            pb = fmaf(zi.y, v[k].y, pb);
            pb = fmaf(zi.z, v[k].z, pb);
            pb = fmaf(zi.w, v[k].w, pb);
            const float r1 = sum8(pa);   // sims1[i][k] partial-sum, all 8 lanes
            const float r2 = sum8(pb);   // sims2 magnitude partial-sum
            const int q = i * 4 + k;
            d1a = fmaf(wA[q], r1, d1a);
            d1b = fmaf(wB[q], r1, d1b);
            d2a = fmaf(wA[q], r2, d2a);
            d2b = fmaf(wB[q], r2, d2b);
        }
    }

    const float o1a = fast_tanh(fmaf( 2.0f, d1a, bb.x));
    const float o1b = fast_tanh(fmaf( 2.0f, d1b, bb.y));
    const float o2a = fast_tanh(fmaf(-2.0f, d2a, bb.x));
    const float o2b = fast_tanh(fmaf(-2.0f, d2b, bb.y));

    *(float2*)(out + (size_t)pair * 16 + p0) = make_float2(o1a, o1b); // 64B/pair contiguous
    *(float2*)(out + (size_t)e2   * 16 + p0) = make_float2(o2a, o2b);
}

extern "C" void kernel_launch(void* const* d_in, const int* in_sizes, int n_in,
                              void* d_out, int out_size, void* d_ws, size_t ws_size,
                              hipStream_t stream) {
    const float* x          = (const float*)d_in[0];
    const float* Maps       = (const float*)d_in[1];
    const float* W1         = (const float*)d_in[2];
    const float* b1         = (const float*)d_in[3];
    const int*   edge_index = (const int*)d_in[4];
    const int*   opp_idx    = (const int*)d_in[5];

    const int E     = in_sizes[5];
    const int EHALF = E / 2;

    const int blocks = (EHALF + PAIRS_PER_BLOCK - 1) / PAIRS_PER_BLOCK;
    sheaf_p8_kernel<<<blocks, TPB, 0, stream>>>(
        x, Maps, W1, b1, edge_index, opp_idx, (float*)d_out, E, EHALF);
}

// Round 7
// 60.710 us; speedup vs baseline: 1.0792x; 1.0792x over previous
//
#include <hip/hip_runtime.h>

constexpr int TPB = 256;
constexpr int PPB = 32;   // pairs per chunk (8 lanes/pair, 256 threads)

__device__ __forceinline__ float fast_tanh(float v) {
    // tanh(x) = 1 - 2/(exp(2x)+1); exact at +/-inf, ~ulp-level error
    float ex = __expf(2.0f * v);
    return 1.0f - 2.0f * __builtin_amdgcn_rcpf(ex + 1.0f);
}

template <int CTRL>
__device__ __forceinline__ float dppadd(float x) {
    return x + __int_as_float(__builtin_amdgcn_update_dpp(
        0, __float_as_int(x), CTRL, 0xf, 0xf, true));
}

// All-reduce over this pair's 8 lanes {quad q, quad q+2} of a 16-lane row:
// row_ror:8 merges the pair's two quads, then two quad_perm rotations.
__device__ __forceinline__ float sum8(float x) {
    x = dppadd<0x128>(x);  // row_ror:8
    x = dppadd<0x39>(x);   // quad_perm [1,2,3,0]
    x = dppadd<0x4E>(x);   // quad_perm [2,3,0,1]
    return x;
}

// Per undirected pair p (e1=p=(s->t), e2=opp_idx[p]):
//   Z = M1*Xs - M2*Xt ; sims1 = 2*Z*Xs^T ; sims2 = -2*Z*Xt^T
//   out[e] = tanh(W1 @ vec(sims_e) + b1)
// Grid-stride over 32-pair chunks with a 3-stage register pipeline:
//   stage n: compute chunk n | x+Maps loads for n+1 in flight | idx loads for n+2.
__global__ __launch_bounds__(TPB) void sheaf_pipe_kernel(
    const float* __restrict__ x,          // (N, 4, 32)
    const float* __restrict__ Maps,       // (E, 4, 4)
    const float* __restrict__ W1,         // (16, 16)
    const float* __restrict__ b1,         // (16,)
    const int*   __restrict__ edge_index, // (2, E)
    const int*   __restrict__ opp_idx,    // (E,)
    float*       __restrict__ out,        // (E, 4, 4)
    int E, int EHALF)
{
    const int tid    = threadIdx.x;
    const int lane16 = tid & 15;
    const int row16  = tid >> 4;
    const int pinr   = (lane16 >> 2) & 1;
    const int slot   = (lane16 & 3) | (((lane16 >> 3) & 1) << 2);
    const int NC     = (EHALF + PPB - 1) / PPB;

    // lane's two W1 rows + biases (loaded once, live across all chunks)
    const int p0 = 2 * slot;
    float wA[16], wB[16];
    {
        const float4* WpA = (const float4*)(W1 + p0 * 16);
        const float4* WpB = (const float4*)(W1 + (p0 + 1) * 16);
        #pragma unroll
        for (int q4 = 0; q4 < 4; ++q4) {
            float4 a = WpA[q4], b = WpB[q4];
            wA[q4*4+0] = a.x; wA[q4*4+1] = a.y; wA[q4*4+2] = a.z; wA[q4*4+3] = a.w;
            wB[q4*4+0] = b.x; wB[q4*4+1] = b.y; wB[q4*4+2] = b.z; wB[q4*4+3] = b.w;
        }
    }
    const float2 bb = *(const float2*)(b1 + p0);

    auto pairOf = [&](int c) { return c * PPB + row16 * 2 + pinr; };

    auto loadIdx = [&](int c, int& s, int& t, int& e2) {
        int pr = pairOf(c);
        int pc = pr < EHALF ? pr : EHALF - 1;
        s  = edge_index[pc];
        t  = edge_index[E + pc];
        e2 = opp_idx[pc];
    };
    auto loadX = [&](int s, int t, float4 (&u)[4], float4 (&v)[4]) {
        const float* xu = x + (size_t)s * 128 + slot * 4;
        const float* xv = x + (size_t)t * 128 + slot * 4;
        #pragma unroll
        for (int d = 0; d < 4; ++d) {
            u[d] = *(const float4*)(xu + d * 32);
            v[d] = *(const float4*)(xv + d * 32);
        }
    };
    auto loadMaps = [&](int c, int e2, float4 (&m1)[4], float4 (&m2)[4]) {
        int pr = pairOf(c);
        int pc = pr < EHALF ? pr : EHALF - 1;
        const float4* M1p = (const float4*)(Maps + (size_t)pc * 16);
        const float4* M2p = (const float4*)(Maps + (size_t)e2 * 16);
        #pragma unroll
        for (int i = 0; i < 4; ++i) { m1[i] = M1p[i]; m2[i] = M2p[i]; }
    };

    auto computeStore = [&](int c, int e2,
                            const float4 (&u)[4], const float4 (&v)[4],
                            const float4 (&m1)[4], const float4 (&m2)[4]) {
        float d1a = 0.f, d1b = 0.f, d2a = 0.f, d2b = 0.f;
        #pragma unroll
        for (int i = 0; i < 4; ++i) {
            const float4 M1 = m1[i], M2 = m2[i];
            float4 zi;
            zi.x = M1.x * u[0].x;            zi.y = M1.x * u[0].y;
            zi.z = M1.x * u[0].z;            zi.w = M1.x * u[0].w;
            zi.x = fmaf(M1.y, u[1].x, zi.x); zi.y = fmaf(M1.y, u[1].y, zi.y);
            zi.z = fmaf(M1.y, u[1].z, zi.z); zi.w = fmaf(M1.y, u[1].w, zi.w);
            zi.x = fmaf(M1.z, u[2].x, zi.x); zi.y = fmaf(M1.z, u[2].y, zi.y);
            zi.z = fmaf(M1.z, u[2].z, zi.z); zi.w = fmaf(M1.z, u[2].w, zi.w);
            zi.x = fmaf(M1.w, u[3].x, zi.x); zi.y = fmaf(M1.w, u[3].y, zi.y);
            zi.z = fmaf(M1.w, u[3].z, zi.z); zi.w = fmaf(M1.w, u[3].w, zi.w);
            zi.x = fmaf(-M2.x, v[0].x, zi.x); zi.y = fmaf(-M2.x, v[0].y, zi.y);
            zi.z = fmaf(-M2.x, v[0].z, zi.z); zi.w = fmaf(-M2.x, v[0].w, zi.w);
            zi.x = fmaf(-M2.y, v[1].x, zi.x); zi.y = fmaf(-M2.y, v[1].y, zi.y);
            zi.z = fmaf(-M2.y, v[1].z, zi.z); zi.w = fmaf(-M2.y, v[1].w, zi.w);
            zi.x = fmaf(-M2.z, v[2].x, zi.x); zi.y = fmaf(-M2.z, v[2].y, zi.y);
            zi.z = fmaf(-M2.z, v[2].z, zi.z); zi.w = fmaf(-M2.z, v[2].w, zi.w);
            zi.x = fmaf(-M2.w, v[3].x, zi.x); zi.y = fmaf(-M2.w, v[3].y, zi.y);
            zi.z = fmaf(-M2.w, v[3].z, zi.z); zi.w = fmaf(-M2.w, v[3].w, zi.w);

            #pragma unroll
            for (int k = 0; k < 4; ++k) {
                float pa = zi.x * u[k].x;
                pa = fmaf(zi.y, u[k].y, pa);
                pa = fmaf(zi.z, u[k].z, pa);
                pa = fmaf(zi.w, u[k].w, pa);
                float pb = zi.x * v[k].x;
                pb = fmaf(zi.y, v[k].y, pb);
                pb = fmaf(zi.z, v[k].z, pb);
                pb = fmaf(zi.w, v[k].w, pb);
                const float r1 = sum8(pa);
                const float r2 = sum8(pb);
                const int q = i * 4 + k;
                d1a = fmaf(wA[q], r1, d1a);
                d1b = fmaf(wB[q], r1, d1b);
                d2a = fmaf(wA[q], r2, d2a);
                d2b = fmaf(wB[q], r2, d2b);
            }
        }
        const float o1a = fast_tanh(fmaf( 2.0f, d1a, bb.x));
        const float o1b = fast_tanh(fmaf( 2.0f, d1b, bb.y));
        const float o2a = fast_tanh(fmaf(-2.0f, d2a, bb.x));
        const float o2b = fast_tanh(fmaf(-2.0f, d2b, bb.y));

        const int pr = pairOf(c);
        if (pr < EHALF) {
            *(float2*)(out + (size_t)pr * 16 + p0) = make_float2(o1a, o1b);
            *(float2*)(out + (size_t)e2 * 16 + p0) = make_float2(o2a, o2b);
        }
    };

    const int G = gridDim.x;
    int cC = blockIdx.x;          // chunk being computed (bufs 0)
    if (cC >= NC) return;

    float4 u0[4], v0[4], m10[4], m20[4];
    float4 u1[4], v1[4], m11[4], m21[4];
    int s1 = 0, t1 = 0, e1 = 0;   // idx of the load-stage chunk
    int sp = 0, tp = 0, ep = 0;   // idx prefetch temp

    int s0, t0, e0;
    loadIdx(cC, s0, t0, e0);      // prologue (latency exposed once per block)
    loadX(s0, t0, u0, v0);
    loadMaps(cC, e0, m10, m20);
    int cL = cC + G;
    if (cL < NC) loadIdx(cL, s1, t1, e1);

    for (;;) {
        // half 1: compute bufs0 @cC; x+Maps -> bufs1 @cL; idx prefetch @cL+G
        int cP = cL + G;
        if (cL < NC) { loadX(s1, t1, u1, v1); loadMaps(cL, e1, m11, m21); }
        if (cP < NC) loadIdx(cP, sp, tp, ep);
        computeStore(cC, e0, u0, v0, m10, m20);
        if (cL >= NC) return;
        cC = cL; cL = cP;

        // half 2: compute bufs1 @cC (e2=e1); x+Maps -> bufs0 @cL (idx sp/tp/ep)
        int cP2 = cL + G;
        if (cL < NC) { loadX(sp, tp, u0, v0); loadMaps(cL, ep, m10, m20); }
        int sq = 0, tq = 0, eq = 0;
        if (cP2 < NC) loadIdx(cP2, sq, tq, eq);
        computeStore(cC, e1, u1, v1, m11, m21);
        if (cL >= NC) return;
        cC = cL; cL = cP2;

        // rotate roles for next iteration
        e0 = ep;                  // e2 of the chunk now in bufs0
        s1 = sq; t1 = tq; e1 = eq;
    }
}

extern "C" void kernel_launch(void* const* d_in, const int* in_sizes, int n_in,
                              void* d_out, int out_size, void* d_ws, size_t ws_size,
                              hipStream_t stream) {
    const float* x          = (const float*)d_in[0];
    const float* Maps       = (const float*)d_in[1];
    const float* W1         = (const float*)d_in[2];
    const float* b1         = (const float*)d_in[3];
    const int*   edge_index = (const int*)d_in[4];
    const int*   opp_idx    = (const int*)d_in[5];

    const int E     = in_sizes[5];
    const int EHALF = E / 2;
    const int NC    = (EHALF + PPB - 1) / PPB;

    const int blocks = NC < 1024 ? NC : 1024;   // ~9 chunks/block: amortize pipeline fill
    sheaf_pipe_kernel<<<blocks, TPB, 0, stream>>>(
        x, Maps, W1, b1, edge_index, opp_idx, (float*)d_out, E, EHALF);
}